// Round 7
// baseline (713.607 us; speedup 1.0000x reference)
//
#include <hip/hip_runtime.h>

#define CIN    256
#define WID    48
#define HWD    2304            // 48*48
#define NTB    64              // ts(16) * b(4)
#define SLICE  (4*CIN*HWD)

// workspace (bytes)
#define WS_AT  0               // A-tiles: 2*36*8192*2B = 1,179,648
#define WS_Y   1179648         // Y bf16 : 64*256*2304*2 = 75,497,472 (ends 76,677,120)

typedef __attribute__((ext_vector_type(8))) short short8v;  // 8 bf16
typedef __attribute__((ext_vector_type(4))) float f32x4;

__device__ __forceinline__ unsigned short f2bf(float f) {
    unsigned u = __float_as_uint(f);
    u = (u + 0x7fffu + ((u >> 16) & 1u)) >> 16;   // RNE
    return (unsigned short)u;
}
__device__ __forceinline__ float bf2f(unsigned short s) {
    return __uint_as_float(((unsigned)s) << 16);
}
__device__ __forceinline__ void gload_lds16(const void* g, void* l) {
    __builtin_amdgcn_global_load_lds(
        (const __attribute__((address_space(1))) unsigned int*)g,
        (__attribute__((address_space(3))) unsigned int*)l, 16, 0, 0);
}

// ---- prep_w: W fp32 -> At bf16, pre-swizzled LDS image, tile order kt2 = g*9 + tap
__global__ __launch_bounds__(256) void prep_w_k(const float* __restrict__ Wt,
                                                unsigned short* __restrict__ At)
{
    const int s = (blockIdx.x * 256 + threadIdx.x) * 8;   // short index < 589824
    const int tile = s >> 13;                 // by*36 + kt2
    const int row  = (s & 8191) >> 6;
    const int colb = (s & 63) * 2;            // byte col (16B-aligned)
    const int by = tile / 36, kt2 = tile - by * 36;
    const int g = kt2 / 9, tap = kt2 - g * 9;
    const int k0 = (colb ^ ((row & 7) << 4)) >> 1;   // elem 0..63, 8-aligned
    const int co = by * 128 + row;
    const float* wp = Wt + (size_t)co * 2304 + (g * 64 + k0) * 9 + tap;
    short8v v;
    #pragma unroll
    for (int j = 0; j < 8; ++j) v[j] = (short)f2bf(wp[j * 9]);
    *(short8v*)(At + s) = v;
}

// ---- conv: single dispatch, 1536 blocks (64tb x 12rt x 2by) = 6/CU even.
// B slab reg-staged from fp32 X per ci-group; A double-buffered via gload_lds.
__global__ __launch_bounds__(256, 2) void conv9_k(
    const float* __restrict__ X, const unsigned short* __restrict__ At,
    const float* __restrict__ Bs, unsigned short* __restrict__ Y)
{
    __shared__ short ldsA[2][8192];    // 2 x 16 KB
    __shared__ short ldsB[19200];      // slab: 300 cells x 128B (37.5 KB)

    const int tid = threadIdx.x;
    const int wv  = tid >> 6, ln = tid & 63;
    const int lr  = ln & 15,  lg = ln >> 4;
    const int wm  = wv >> 1,  wn = wv & 1;

    // chunked XCD swizzle: 192 consecutive logical wgs per XCD; by-pairs adjacent
    const int orig = blockIdx.x;
    const int wg   = (orig & 7) * 192 + (orig >> 3);
    const int by   = wg & 1;
    const int pair = wg >> 1;            // 0..767
    const int tb   = pair / 12;
    const int rt   = pair - tb * 12;     // 0..11 (4 image rows each)

    // B-fragment slab pixel offsets (fixed per thread)
    int boff[6];
    #pragma unroll
    for (int ni = 0; ni < 6; ++ni) {
        const int p = wn * 96 + ni * 16 + lr;
        const int r = p / 48, c = p - r * 48;
        boff[ni] = (r + 1) * 50 + (c + 1);
    }
    // A ds_read swizzled column offsets (shorts)
    const int cx0 = ((lg << 4) ^ ((lr & 7) << 4)) >> 1;
    const int cx1 = ((64 | (lg << 4)) ^ ((lr & 7) << 4)) >> 1;

    const unsigned short* Asrc = At + (size_t)by * 36 * 8192 + wv * 2048 + ln * 8;
    const float* Xb = X + (size_t)tb * CIN * HWD;

    const int col  = ln - 1;                       // slab col -1..62 (use <48)
    const bool colv = (unsigned)col < 48u;

    f32x4 acc[4][6];
    const f32x4 zero = {0.f, 0.f, 0.f, 0.f};
    #pragma unroll
    for (int i = 0; i < 4; ++i)
        #pragma unroll
        for (int j = 0; j < 6; ++j) acc[i][j] = zero;

    // prologue: stage A(0)
    #pragma unroll
    for (int i = 0; i < 4; ++i)
        gload_lds16(Asrc + i * 512, &ldsA[0][wv * 2048 + i * 512]);

    for (int g = 0; g < 4; ++g) {
        const unsigned short* Ag = Asrc + (size_t)g * 9 * 8192;

        // ---- stage B slab for this ci-group: 96 wave-tasks, reg->LDS
        if (ln < 50) {
            #pragma unroll
            for (int j = 0; j < 24; ++j) {
                const int gt = wv * 24 + j;           // wave-uniform
                const int cq = gt / 6, r6 = gt - (gt / 6) * 6;
                const int row = rt * 4 - 1 + r6;
                const bool v = colv && ((unsigned)row < 48u);
                const int off = v ? (row * WID + col) : 0;
                const float* xp = Xb + (size_t)(g * 64 + cq * 4) * HWD + off;
                const float f0 = v ? xp[0]           : 0.f;
                const float f1 = v ? xp[HWD]         : 0.f;
                const float f2 = v ? xp[2 * HWD]     : 0.f;
                const float f3 = v ? xp[3 * HWD]     : 0.f;
                const unsigned lo = (unsigned)f2bf(f0) | ((unsigned)f2bf(f1) << 16);
                const unsigned hi = (unsigned)f2bf(f2) | ((unsigned)f2bf(f3) << 16);
                const int p   = r6 * 50 + ln;         // cell 0..299
                const int byt = p * 128 + (((cq >> 1) ^ (p & 7)) << 4) + (cq & 1) * 8;
                uint2 u; u.x = lo; u.y = hi;
                *(uint2*)((char*)ldsB + byt) = u;     // ds_write_b64
            }
        }
        asm volatile("s_waitcnt vmcnt(0) lgkmcnt(0)" ::: "memory");
        __builtin_amdgcn_sched_barrier(0);
        __builtin_amdgcn_s_barrier();                 // slab + A tile ready

        #pragma unroll
        for (int tap = 0; tap < 9; ++tap) {
            const int cur = (g ^ tap) & 1;            // (g*9+tap)&1
            const short* curA = ldsA[cur];
            if (tap < 8 || g < 3) {                   // prefetch next A tile
                const unsigned short* an = Ag + (size_t)(tap + 1) * 8192;
                #pragma unroll
                for (int i = 0; i < 4; ++i)
                    gload_lds16(an + i * 512, &ldsA[cur ^ 1][wv * 2048 + i * 512]);
            }
            const int toff = (tap / 3 - 1) * 50 + (tap % 3 - 1);
            #pragma unroll
            for (int kh = 0; kh < 2; ++kh) {
                const int cx = kh ? cx1 : cx0;
                short8v a_[4], b_[6];
                #pragma unroll
                for (int mi = 0; mi < 4; ++mi)
                    a_[mi] = *(const short8v*)&curA[(wm * 64 + mi * 16 + lr) * 64 + cx];
                #pragma unroll
                for (int ni = 0; ni < 6; ++ni) {
                    const int sp = boff[ni] + toff;
                    b_[ni] = *(const short8v*)&ldsB[sp * 64 + ((((kh << 2) | lg) ^ (sp & 7)) << 3)];
                }
                __builtin_amdgcn_s_setprio(1);
                #pragma unroll
                for (int mi = 0; mi < 4; ++mi)
                    #pragma unroll
                    for (int ni = 0; ni < 6; ++ni)
                        acc[mi][ni] = __builtin_amdgcn_mfma_f32_16x16x32_bf16(
                            a_[mi], b_[ni], acc[mi][ni], 0, 0, 0);
                __builtin_amdgcn_s_setprio(0);
            }
            asm volatile("s_waitcnt vmcnt(0)" ::: "memory");   // A(next): 4 loads, covered
            __builtin_amdgcn_sched_barrier(0);
            __builtin_amdgcn_s_barrier();
        }
    }

    // epilogue: D row=(lane>>4)*4+r (m), col=lane&15 (px)
    const int nbase = rt * 192 + wn * 96;
    #pragma unroll
    for (int mi = 0; mi < 4; ++mi) {
        const int m = by * 128 + wm * 64 + mi * 16 + lg * 4;
        const f32x4 b4 = *(const f32x4*)&Bs[m];
        #pragma unroll
        for (int r = 0; r < 4; ++r) {
            unsigned short* yp = Y + ((size_t)tb * CIN + m + r) * HWD + nbase;
            #pragma unroll
            for (int ni = 0; ni < 6; ++ni)
                yp[ni * 16 + lr] = f2bf(acc[mi][ni][r] + b4[r]);
        }
    }
}

// ---- LI scan in place on bf16 Y, 4 elems/thread
__global__ __launch_bounds__(256) void li_scan_k(uint2* __restrict__ Y)
{
    const int n = blockIdx.x * 256 + threadIdx.x;
    float v[4] = {0.f, 0.f, 0.f, 0.f}, c[4] = {0.f, 0.f, 0.f, 0.f};
    #pragma unroll
    for (int t = 0; t < 16; ++t) {
        const size_t idx = (size_t)t * (SLICE / 4) + n;
        uint2 u = Y[idx];
        float x[4] = { bf2f((unsigned short)(u.x & 0xffff)), bf2f((unsigned short)(u.x >> 16)),
                       bf2f((unsigned short)(u.y & 0xffff)), bf2f((unsigned short)(u.y >> 16)) };
        #pragma unroll
        for (int e = 0; e < 4; ++e) {
            v[e] = v[e] + 0.1f * ((0.0f - v[e]) + c[e]);
            c[e] = c[e] - 0.2f * c[e] + x[e];
        }
        u.x = (unsigned)f2bf(v[0]) | ((unsigned)f2bf(v[1]) << 16);
        u.y = (unsigned)f2bf(v[2]) | ((unsigned)f2bf(v[3]) << 16);
        Y[idx] = u;
    }
}

// ---- 1x1 heads, 2 pixels/thread
__global__ __launch_bounds__(256) void heads_k(
    const unsigned int* __restrict__ V,
    const float* __restrict__ bw, const float* __restrict__ bb,
    const float* __restrict__ cw, const float* __restrict__ cb,
    float* __restrict__ out)
{
    const int n = blockIdx.x * 256 + threadIdx.x;
    const int tb  = n / (HWD / 2);
    const int hw2 = n - tb * (HWD / 2);
    const unsigned int* vp = V + (size_t)tb * CIN * (HWD / 2) + hw2;

    float b0[12], b1[12], cl0[9], cl1[9];
    #pragma unroll
    for (int o = 0; o < 12; ++o) { b0[o] = bb[o]; b1[o] = bb[o]; }
    #pragma unroll
    for (int o = 0; o < 9;  ++o) { cl0[o] = cb[o]; cl1[o] = cb[o]; }

    for (int ci = 0; ci < CIN; ++ci) {
        const unsigned u = vp[(size_t)ci * (HWD / 2)];
        const float lo = bf2f((unsigned short)(u & 0xffff));
        const float hi = bf2f((unsigned short)(u >> 16));
        #pragma unroll
        for (int o = 0; o < 12; ++o) {
            const float w = bw[o * CIN + ci];
            b0[o] += lo * w; b1[o] += hi * w;
        }
        #pragma unroll
        for (int o = 0; o < 9; ++o) {
            const float w = cw[o * CIN + ci];
            cl0[o] += lo * w; cl1[o] += hi * w;
        }
    }

    const int hw = hw2 * 2;
    float* ob = out + (size_t)tb * 12 * HWD + hw;
    #pragma unroll
    for (int o = 0; o < 12; ++o) { ob[(size_t)o * HWD] = b0[o]; ob[(size_t)o * HWD + 1] = b1[o]; }
    float* oc = out + (size_t)12 * NTB * HWD + (size_t)tb * 9 * HWD + hw;
    #pragma unroll
    for (int o = 0; o < 9;  ++o) { oc[(size_t)o * HWD] = cl0[o]; oc[(size_t)o * HWD + 1] = cl1[o]; }
}

extern "C" void kernel_launch(void* const* d_in, const int* in_sizes, int n_in,
                              void* d_out, int out_size, void* d_ws, size_t ws_size,
                              hipStream_t stream)
{
    const float* X   = (const float*)d_in[0];  // (16,4,256,48,48)
    const float* cw3 = (const float*)d_in[1];  // (256,256,3,3)
    const float* cb3 = (const float*)d_in[2];  // (256,)
    const float* bw  = (const float*)d_in[3];
    const float* bb  = (const float*)d_in[4];
    const float* clw = (const float*)d_in[5];
    const float* clb = (const float*)d_in[6];
    float* out = (float*)d_out;

    unsigned short* At = (unsigned short*)((char*)d_ws + WS_AT);
    unsigned short* Y  = (unsigned short*)((char*)d_ws + WS_Y);

    prep_w_k<<<288, 256, 0, stream>>>(cw3, At);
    conv9_k <<<1536, 256, 0, stream>>>(X, At, cb3, Y);
    li_scan_k<<<SLICE / 1024, 256, 0, stream>>>((uint2*)Y);
    heads_k  <<<NTB * HWD / 512, 256, 0, stream>>>((const unsigned int*)Y,
                                                   bw, bb, clw, clb, out);
}

// Round 8
// 487.705 us; speedup vs baseline: 1.4632x; 1.4632x over previous
//
#include <hip/hip_runtime.h>

#define CIN    256
#define WID    48
#define HWD    2304            // 48*48
#define NTB    64              // ts(16) * b(4)
#define SLICE  (4*CIN*HWD)

// ws layout: Xt bf16 [64tb][4g][2304px][64ci] = 75,497,472 ; Y bf16 = 75,497,472 (exactly 151 MB)
#define WS_Y   75497472
// d_out scratch layout: [0,8192) zero page ; [8192, 8192+1179648) A-tiles (heads overwrites all at end)

typedef __attribute__((ext_vector_type(8))) short short8v;  // 8 bf16
typedef __attribute__((ext_vector_type(4))) float f32x4;

__device__ __forceinline__ unsigned short f2bf(float f) {
    unsigned u = __float_as_uint(f);
    u = (u + 0x7fffu + ((u >> 16) & 1u)) >> 16;   // RNE
    return (unsigned short)u;
}
__device__ __forceinline__ float bf2f(unsigned short s) {
    return __uint_as_float(((unsigned)s) << 16);
}
__device__ __forceinline__ void gload_lds16(const void* g, void* l) {
    __builtin_amdgcn_global_load_lds(
        (const __attribute__((address_space(1))) unsigned int*)g,
        (__attribute__((address_space(3))) unsigned int*)l, 16, 0, 0);
}

// ---- prep_w: W fp32 -> At bf16, pre-swizzled LDS image, tile order kt2 = g*9 + tap
__global__ __launch_bounds__(256) void prep_w_k(const float* __restrict__ Wt,
                                                unsigned short* __restrict__ At)
{
    const int s = (blockIdx.x * 256 + threadIdx.x) * 8;   // short index < 589824
    const int tile = s >> 13;                 // by*36 + kt2
    const int row  = (s & 8191) >> 6;
    const int colb = (s & 63) * 2;            // byte col (16B-aligned)
    const int by = tile / 36, kt2 = tile - by * 36;
    const int g = kt2 / 9, tap = kt2 - g * 9;
    const int k0 = (colb ^ ((row & 7) << 4)) >> 1;   // elem 0..63, 8-aligned
    const int co = by * 128 + row;
    const float* wp = Wt + (size_t)co * 2304 + (g * 64 + k0) * 9 + tap;
    short8v v;
    #pragma unroll
    for (int j = 0; j < 8; ++j) v[j] = (short)f2bf(wp[j * 9]);
    *(short8v*)(At + s) = v;
}

// ---- prep_x: X fp32 [64tb][ci][px] -> Xt bf16 [64tb][g][px(2304)][64ci] (no padding)
__global__ __launch_bounds__(256) void prep_x_k(const float* __restrict__ X,
                                                unsigned short* __restrict__ Xt)
{
    __shared__ unsigned short t_[64][72];
    const int tid = threadIdx.x;
    const int px0 = blockIdx.x * 64;
    const int g   = blockIdx.y;               // ci group of 64
    const int tb  = blockIdx.z;

    const int ci_l = tid >> 2, pg = (tid & 3) * 16;
    const float* xp = X + ((size_t)tb * CIN + g * 64 + ci_l) * HWD + px0 + pg;
    #pragma unroll
    for (int q = 0; q < 4; ++q) {
        f32x4 v = *(const f32x4*)(xp + q * 4);
        #pragma unroll
        for (int e = 0; e < 4; ++e)
            t_[pg + q * 4 + e][ci_l] = f2bf(v[e]);
    }
    __syncthreads();
    const int px_l = tid >> 2, cg = (tid & 3) * 16;
    unsigned short* op = Xt + (((size_t)tb * 4 + g) * HWD + px0 + px_l) * 64 + cg;
    *(short8v*)op       = *(const short8v*)&t_[px_l][cg];
    *(short8v*)(op + 8) = *(const short8v*)&t_[px_l][cg + 8];
}

// ---- conv: 1536 blocks (64tb x 12rt x 2by) = exactly 6/CU, 2 resident, even rounds.
// B slab (6 rows x 50 cols x 64ci) staged per ci-group from bf16 Xt; A double-buffered.
__global__ __launch_bounds__(256, 2) void conv10_k(
    const unsigned short* __restrict__ Xt, const unsigned short* __restrict__ At,
    const unsigned short* __restrict__ zp,
    const float* __restrict__ Bs, unsigned short* __restrict__ Y)
{
    __shared__ short ldsA[2][8192];    // 2 x 16 KB
    __shared__ short ldsB[19200];      // slab: 300 cells x 128B (37.5 KB)

    const int tid = threadIdx.x;
    const int wv  = tid >> 6, ln = tid & 63;
    const int lr  = ln & 15,  lg = ln >> 4;
    const int wm  = wv >> 1,  wn = wv & 1;

    // chunked XCD swizzle: 192 consecutive logical wgs per XCD; by-pairs adjacent
    const int orig = blockIdx.x;
    const int wg   = (orig & 7) * 192 + (orig >> 3);
    const int by   = wg & 1;
    const int pair = wg >> 1;            // 0..767
    const int tb   = pair / 12;
    const int rt   = pair - tb * 12;     // 0..11 (4 image rows each)

    // B-fragment slab pixel offsets (fixed per thread)
    int boff[6];
    #pragma unroll
    for (int ni = 0; ni < 6; ++ni) {
        const int p = wn * 96 + ni * 16 + lr;
        const int r = p / 48, c = p - r * 48;
        boff[ni] = (r + 1) * 50 + (c + 1);
    }
    // A ds_read swizzled column offsets (shorts)
    const int cx0 = ((lg << 4) ^ ((lr & 7) << 4)) >> 1;
    const int cx1 = ((64 | (lg << 4)) ^ ((lr & 7) << 4)) >> 1;

    const unsigned short* Asrc = At + (size_t)by * 36 * 8192 + wv * 2048 + ln * 8;
    const unsigned short* Xtb  = Xt + (size_t)tb * 4 * HWD * 64;

    f32x4 acc[4][6];
    const f32x4 zero = {0.f, 0.f, 0.f, 0.f};
    #pragma unroll
    for (int i = 0; i < 4; ++i)
        #pragma unroll
        for (int j = 0; j < 6; ++j) acc[i][j] = zero;

    // stage B slab for ci-group g: 2304 interior 16B chunks (halo cols untouched)
    auto stage_slab = [&](int g) {
        const unsigned short* Xg = Xtb + (size_t)g * HWD * 64;
        #pragma unroll
        for (int j = 0; j < 9; ++j) {
            const int cc  = tid + 256 * j;          // 0..2303
            const int r6  = cc / 384;               // wave-uniform (64 | 384)
            const int rem = cc - r6 * 384;
            const int pxc = rem >> 3, k = cc & 7;
            const int sp  = r6 * 50 + 1 + pxc;      // slab cell (col 1..48)
            const int row = rt * 4 - 1 + r6;
            const unsigned short* src = ((unsigned)row < 48u)
                ? Xg + (((size_t)row * WID + pxc) * 64 + ((k ^ (sp & 7)) << 3))
                : zp + ln * 8;
            gload_lds16(src, &ldsB[sp * 64 + k * 8]);
        }
    };

    // prologue: zero halo-col cells (cols 0 and 49), stage A(0,0) + slab(0)
    if (tid < 96) {
        const int c12 = tid >> 3;                   // 0..11
        const int sp  = (c12 >> 1) * 50 + (c12 & 1) * 49;
        short8v z = {0,0,0,0,0,0,0,0};
        *(short8v*)&ldsB[sp * 64 + (tid & 7) * 8] = z;
    }
    #pragma unroll
    for (int i = 0; i < 4; ++i)
        gload_lds16(Asrc + i * 512, &ldsA[0][wv * 2048 + i * 512]);
    stage_slab(0);
    __syncthreads();                                // drains vm+lgkm, barrier

    for (int g = 0; g < 4; ++g) {
        const unsigned short* Ag = Asrc + (size_t)g * 9 * 8192;
        if (g > 0) {
            stage_slab(g);                          // A(g,0) already staged at g-1 tap8
            asm volatile("s_waitcnt vmcnt(0)" ::: "memory");
            __builtin_amdgcn_sched_barrier(0);
            __builtin_amdgcn_s_barrier();
        }

        #pragma unroll
        for (int tap = 0; tap < 9; ++tap) {
            const int cur = (g + tap) & 1;
            const short* curA = ldsA[cur];
            if (tap < 8 || g < 3) {                 // prefetch next A tile (contiguous kt2)
                const unsigned short* an = Ag + (size_t)(tap + 1) * 8192;
                #pragma unroll
                for (int i = 0; i < 4; ++i)
                    gload_lds16(an + i * 512, &ldsA[cur ^ 1][wv * 2048 + i * 512]);
            }
            const int toff = (tap / 3 - 1) * 50 + (tap % 3 - 1);
            #pragma unroll
            for (int kh = 0; kh < 2; ++kh) {
                const int cx = kh ? cx1 : cx0;
                short8v a_[4], b_[6];
                #pragma unroll
                for (int mi = 0; mi < 4; ++mi)
                    a_[mi] = *(const short8v*)&curA[(wm * 64 + mi * 16 + lr) * 64 + cx];
                #pragma unroll
                for (int ni = 0; ni < 6; ++ni) {
                    const int sp = boff[ni] + toff;
                    b_[ni] = *(const short8v*)&ldsB[sp * 64 + ((((kh << 2) | lg) ^ (sp & 7)) << 3)];
                }
                __builtin_amdgcn_s_setprio(1);
                #pragma unroll
                for (int mi = 0; mi < 4; ++mi)
                    #pragma unroll
                    for (int ni = 0; ni < 6; ++ni)
                        acc[mi][ni] = __builtin_amdgcn_mfma_f32_16x16x32_bf16(
                            a_[mi], b_[ni], acc[mi][ni], 0, 0, 0);
                __builtin_amdgcn_s_setprio(0);
            }
            asm volatile("s_waitcnt vmcnt(0)" ::: "memory");   // A(next): 4 L2-warm loads
            __builtin_amdgcn_sched_barrier(0);
            __builtin_amdgcn_s_barrier();
        }
    }

    // epilogue: D row=(lane>>4)*4+r (m), col=lane&15 (px)
    const int nbase = rt * 192 + wn * 96;
    #pragma unroll
    for (int mi = 0; mi < 4; ++mi) {
        const int m = by * 128 + wm * 64 + mi * 16 + lg * 4;
        const f32x4 b4 = *(const f32x4*)&Bs[m];
        #pragma unroll
        for (int r = 0; r < 4; ++r) {
            unsigned short* yp = Y + ((size_t)tb * CIN + m + r) * HWD + nbase;
            #pragma unroll
            for (int ni = 0; ni < 6; ++ni)
                yp[ni * 16 + lr] = f2bf(acc[mi][ni][r] + b4[r]);
        }
    }
}

// ---- LI scan in place on bf16 Y, 4 elems/thread
__global__ __launch_bounds__(256) void li_scan_k(uint2* __restrict__ Y)
{
    const int n = blockIdx.x * 256 + threadIdx.x;
    float v[4] = {0.f, 0.f, 0.f, 0.f}, c[4] = {0.f, 0.f, 0.f, 0.f};
    #pragma unroll
    for (int t = 0; t < 16; ++t) {
        const size_t idx = (size_t)t * (SLICE / 4) + n;
        uint2 u = Y[idx];
        float x[4] = { bf2f((unsigned short)(u.x & 0xffff)), bf2f((unsigned short)(u.x >> 16)),
                       bf2f((unsigned short)(u.y & 0xffff)), bf2f((unsigned short)(u.y >> 16)) };
        #pragma unroll
        for (int e = 0; e < 4; ++e) {
            v[e] = v[e] + 0.1f * ((0.0f - v[e]) + c[e]);
            c[e] = c[e] - 0.2f * c[e] + x[e];
        }
        u.x = (unsigned)f2bf(v[0]) | ((unsigned)f2bf(v[1]) << 16);
        u.y = (unsigned)f2bf(v[2]) | ((unsigned)f2bf(v[3]) << 16);
        Y[idx] = u;
    }
}

// ---- 1x1 heads, 2 pixels/thread
__global__ __launch_bounds__(256) void heads_k(
    const unsigned int* __restrict__ V,
    const float* __restrict__ bw, const float* __restrict__ bb,
    const float* __restrict__ cw, const float* __restrict__ cb,
    float* __restrict__ out)
{
    const int n = blockIdx.x * 256 + threadIdx.x;
    const int tb  = n / (HWD / 2);
    const int hw2 = n - tb * (HWD / 2);
    const unsigned int* vp = V + (size_t)tb * CIN * (HWD / 2) + hw2;

    float b0[12], b1[12], cl0[9], cl1[9];
    #pragma unroll
    for (int o = 0; o < 12; ++o) { b0[o] = bb[o]; b1[o] = bb[o]; }
    #pragma unroll
    for (int o = 0; o < 9;  ++o) { cl0[o] = cb[o]; cl1[o] = cb[o]; }

    for (int ci = 0; ci < CIN; ++ci) {
        const unsigned u = vp[(size_t)ci * (HWD / 2)];
        const float lo = bf2f((unsigned short)(u & 0xffff));
        const float hi = bf2f((unsigned short)(u >> 16));
        #pragma unroll
        for (int o = 0; o < 12; ++o) {
            const float w = bw[o * CIN + ci];
            b0[o] += lo * w; b1[o] += hi * w;
        }
        #pragma unroll
        for (int o = 0; o < 9; ++o) {
            const float w = cw[o * CIN + ci];
            cl0[o] += lo * w; cl1[o] += hi * w;
        }
    }

    const int hw = hw2 * 2;
    float* ob = out + (size_t)tb * 12 * HWD + hw;
    #pragma unroll
    for (int o = 0; o < 12; ++o) { ob[(size_t)o * HWD] = b0[o]; ob[(size_t)o * HWD + 1] = b1[o]; }
    float* oc = out + (size_t)12 * NTB * HWD + (size_t)tb * 9 * HWD + hw;
    #pragma unroll
    for (int o = 0; o < 9;  ++o) { oc[(size_t)o * HWD] = cl0[o]; oc[(size_t)o * HWD + 1] = cl1[o]; }
}

extern "C" void kernel_launch(void* const* d_in, const int* in_sizes, int n_in,
                              void* d_out, int out_size, void* d_ws, size_t ws_size,
                              hipStream_t stream)
{
    const float* X   = (const float*)d_in[0];  // (16,4,256,48,48)
    const float* cw3 = (const float*)d_in[1];  // (256,256,3,3)
    const float* cb3 = (const float*)d_in[2];  // (256,)
    const float* bw  = (const float*)d_in[3];
    const float* bb  = (const float*)d_in[4];
    const float* clw = (const float*)d_in[5];
    const float* clb = (const float*)d_in[6];
    float* out = (float*)d_out;

    unsigned short* Xt = (unsigned short*)d_ws;                       // 75.5 MB
    unsigned short* Y  = (unsigned short*)((char*)d_ws + WS_Y);       // 75.5 MB

    const unsigned short* zp = (const unsigned short*)d_out;          // 8 KB zeros
    unsigned short* At = (unsigned short*)((char*)d_out + 8192);      // 1.18 MB (scratch in out)

    hipMemsetAsync(d_out, 0, 8192, stream);                           // zero page
    prep_w_k<<<288, 256, 0, stream>>>(cw3, At);
    prep_x_k<<<dim3(36, 4, 64), 256, 0, stream>>>(X, Xt);
    conv10_k<<<1536, 256, 0, stream>>>(Xt, At, zp, cb3, Y);
    li_scan_k<<<SLICE / 1024, 256, 0, stream>>>((uint2*)Y);
    heads_k  <<<NTB * HWD / 512, 256, 0, stream>>>((const unsigned int*)Y,
                                                   bw, bb, clw, clb, out);
}

// Round 10
// 412.999 us; speedup vs baseline: 1.7279x; 1.1809x over previous
//
#include <hip/hip_runtime.h>

#define CIN    256
#define WID    48
#define HWD    2304            // 48*48
#define PHW    2500            // 50*50 padded
#define NTB    64              // ts(16) * b(4)
#define SLICE  (4*CIN*HWD)

// ws (bytes): Xtp half [32tb][8 g2][2500 pp][32ci] bf16 = 40,960,000
//             At [2by][72 kt][4096 shorts]          =  1,179,648
//             Y bf16                                 = 75,497,472  (ends 117,637,120)
#define WS_XT  0
#define WS_AT  40960000
#define WS_Y   42139648

typedef __attribute__((ext_vector_type(8))) short short8v;  // 8 bf16
typedef __attribute__((ext_vector_type(4))) float f32x4;

__device__ __forceinline__ unsigned short f2bf(float f) {
    unsigned u = __float_as_uint(f);
    u = (u + 0x7fffu + ((u >> 16) & 1u)) >> 16;   // RNE
    return (unsigned short)u;
}
__device__ __forceinline__ float bf2f(unsigned short s) {
    return __uint_as_float(((unsigned)s) << 16);
}
__device__ __forceinline__ void gload_lds16(const void* g, void* l) {
    __builtin_amdgcn_global_load_lds(
        (const __attribute__((address_space(1))) unsigned int*)g,
        (__attribute__((address_space(3))) unsigned int*)l, 16, 0, 0);
}

// ---- prep_w: W fp32 -> At bf16, dest-linear with pair-XOR swizzle baked.
// tile kt2 = g2*9+tap (g2 = 32-ci group). chunk c: P=(c>>3)&63, s=c&7;
// s'=s^(P&7); row=2P+(s'>>2); ci-chunk=s'&3  ->  W[co][g2*32+cik*8+j][tap]
__global__ __launch_bounds__(256) void prep_w_k(const float* __restrict__ Wt,
                                                unsigned short* __restrict__ At)
{
    const int c = blockIdx.x * 256 + threadIdx.x;   // chunk id < 73728
    const int tile = c >> 9;                        // by*72 + kt2
    const int P = (c >> 3) & 63;
    const int s = c & 7;
    const int by = tile / 72, kt2 = tile - by * 72;
    const int g2 = kt2 / 9, tap = kt2 - g2 * 9;
    const int sp = s ^ (P & 7);
    const int row = P * 2 + (sp >> 2);
    const int cik = sp & 3;
    const int co = by * 128 + row;
    const float* wp = Wt + (size_t)co * 2304 + (g2 * 32 + cik * 8) * 9 + tap;
    short8v v;
    #pragma unroll
    for (int j = 0; j < 8; ++j) v[j] = (short)f2bf(wp[j * 9]);
    *(short8v*)(At + (size_t)c * 8) = v;
}

// ---- prep_x: X fp32 [32tb][ci][px] -> Xtp bf16 [32tb][g2(8)][pp(2500)][32ci]
// halo stays zero from one-time memset
__global__ __launch_bounds__(256) void prep_x_k(const float* __restrict__ X,
                                                unsigned short* __restrict__ Xtp)
{
    __shared__ unsigned short t_[64][72];
    const int tid = threadIdx.x;
    const int px0 = blockIdx.x * 64;
    const int g   = blockIdx.y;               // 64-ci group (2 g2 halves)
    const int tb  = blockIdx.z;

    const int ci_l = tid >> 2, pg = (tid & 3) * 16;
    const float* xp = X + ((size_t)tb * CIN + g * 64 + ci_l) * HWD + px0 + pg;
    #pragma unroll
    for (int q = 0; q < 4; ++q) {
        f32x4 v = *(const f32x4*)(xp + q * 4);
        #pragma unroll
        for (int e = 0; e < 4; ++e)
            t_[pg + q * 4 + e][ci_l] = f2bf(v[e]);
    }
    __syncthreads();
    const int px_l = tid >> 2, cg = (tid & 3) * 16;
    const int p  = px0 + px_l;
    const int pp = p + (p / WID) * 2 + 51;    // (h+1)*50 + (w+1)
    const int g2 = g * 2 + (cg >> 5);
    unsigned short* op = Xtp + (((size_t)tb * 8 + g2) * PHW + pp) * 32 + (cg & 31);
    *(short8v*)op       = *(const short8v*)&t_[px_l][cg];
    *(short8v*)(op + 8) = *(const short8v*)&t_[px_l][cg + 8];
}

// ---- conv: K=32 steps, small LDS (34.75 KB) -> 3-4 blocks/CU, grid 768 = even 3/CU.
// BM=128 BN=192; slab per 32-ci group staged every 9 taps; A dbuf via gload_lds.
__global__ __launch_bounds__(256, 3) void conv11_k(
    const unsigned short* __restrict__ Xtp, const unsigned short* __restrict__ At,
    const float* __restrict__ Bs, unsigned short* __restrict__ Y, int tb_base)
{
    __shared__ short ldsA[2][4096];    // 2 x 8 KB  (64 pairs x 128B)
    __shared__ short ldsB[9600];       // slab: 150 px-pairs x 128B (18.75 KB)

    const int tid = threadIdx.x;
    const int wv  = tid >> 6, ln = tid & 63;
    const int lr  = ln & 15,  lg = ln >> 4;        // lg 0..3: ci chunk of 8
    const int wm  = wv >> 1,  wn = wv & 1;

    // bijective XCD swizzle, nwg=768 (q=96)
    const int orig = blockIdx.x;
    const int wg   = (orig & 7) * 96 + (orig >> 3);
    const int by   = wg & 1;
    const int pair = wg >> 1;            // 0..383
    const int tb_l = pair / 12;
    const int rt   = pair - tb_l * 12;   // 0..11 (4 image rows each)

    // B-fragment slab pixel indices (fixed per thread)
    int boff[6];
    #pragma unroll
    for (int ni = 0; ni < 6; ++ni) {
        const int p = wn * 96 + ni * 16 + lr;
        const int r = p / 48, c = p - r * 48;
        boff[ni] = (r + 1) * 50 + (c + 1);
    }

    const unsigned short* Asrc  = At + (size_t)by * 72 * 4096;
    const unsigned short* slab0 = Xtp + (((size_t)tb_l * 8) * PHW + rt * 200) * 32;

    f32x4 acc[4][6];
    const f32x4 zero = {0.f, 0.f, 0.f, 0.f};
    #pragma unroll
    for (int i = 0; i < 4; ++i)
        #pragma unroll
        for (int j = 0; j < 6; ++j) acc[i][j] = zero;

    // A tile kt2 -> buf (512 chunks, 2/thread, lane-linear dest)
    auto stageA = [&](int kt2, int buf) {
        const unsigned short* ap = Asrc + (size_t)kt2 * 4096 + tid * 8;
        gload_lds16(ap,        &ldsA[buf][tid * 8]);
        gload_lds16(ap + 2048, &ldsA[buf][2048 + tid * 8]);
    };
    // B slab for g2 (1200 chunks, <=5/thread, lane-linear dest, source pre-swizzled)
    auto stageB = [&](int g2) {
        const unsigned short* sg = slab0 + (size_t)g2 * PHW * 32;
        #pragma unroll
        for (int j = 0; j < 5; ++j) {
            const int cc = tid + 256 * j;
            if (cc < 1200) {
                const int P = cc >> 3, s = cc & 7;
                const int s2 = s ^ (P & 7);
                const int px = P * 2 + (s2 >> 2);
                gload_lds16(sg + px * 32 + (s2 & 3) * 8, &ldsB[cc * 8]);
            }
        }
    };

    stageA(0, 0);
    stageB(0);
    asm volatile("s_waitcnt vmcnt(0)" ::: "memory");
    __builtin_amdgcn_sched_barrier(0);
    __builtin_amdgcn_s_barrier();

    for (int g2 = 0; g2 < 8; ++g2) {
        #pragma unroll
        for (int tap = 0; tap < 9; ++tap) {
            const int kt2 = g2 * 9 + tap;
            const int cur = kt2 & 1;
            if (kt2 < 71) stageA(kt2 + 1, cur ^ 1);
            const int toff = (tap / 3 - 1) * 50 + (tap % 3) - 1;

            short8v a_[4], b_[6];
            #pragma unroll
            for (int mi = 0; mi < 4; ++mi) {
                const int r = wm * 64 + mi * 16 + lr;
                const int P = r >> 1;
                const int s = (((r & 1) << 2) | lg) ^ (P & 7);
                a_[mi] = *(const short8v*)&ldsA[cur][P * 64 + s * 8];   // pair-row = 64 shorts
            }
            #pragma unroll
            for (int ni = 0; ni < 6; ++ni) {
                const int sp = boff[ni] + toff;
                const int P = sp >> 1;
                const int s = (((sp & 1) << 2) | lg) ^ (P & 7);
                b_[ni] = *(const short8v*)&ldsB[P * 64 + s * 8];        // pair-row = 64 shorts
            }
            __builtin_amdgcn_s_setprio(1);
            #pragma unroll
            for (int mi = 0; mi < 4; ++mi)
                #pragma unroll
                for (int ni = 0; ni < 6; ++ni)
                    acc[mi][ni] = __builtin_amdgcn_mfma_f32_16x16x32_bf16(
                        a_[mi], b_[ni], acc[mi][ni], 0, 0, 0);
            __builtin_amdgcn_s_setprio(0);

            asm volatile("s_waitcnt vmcnt(0)" ::: "memory");
            __builtin_amdgcn_sched_barrier(0);
            __builtin_amdgcn_s_barrier();              // step done; bufs consistent
            if (tap == 8 && g2 < 7) {                  // re-stage slab for next g2
                stageB(g2 + 1);
                asm volatile("s_waitcnt vmcnt(0)" ::: "memory");
                __builtin_amdgcn_sched_barrier(0);
                __builtin_amdgcn_s_barrier();
            }
        }
    }

    // epilogue: D row=(lane>>4)*4+r (m), col=lane&15 (px)
    const int tbg   = tb_base + tb_l;
    const int nbase = rt * 192 + wn * 96;
    #pragma unroll
    for (int mi = 0; mi < 4; ++mi) {
        const int m = by * 128 + wm * 64 + mi * 16 + lg * 4;
        const f32x4 b4 = *(const f32x4*)&Bs[m];
        #pragma unroll
        for (int r = 0; r < 4; ++r) {
            unsigned short* yp = Y + ((size_t)tbg * CIN + m + r) * HWD + nbase;
            #pragma unroll
            for (int ni = 0; ni < 6; ++ni)
                yp[ni * 16 + lr] = f2bf(acc[mi][ni][r] + b4[r]);
        }
    }
}

// ---- LI scan in place on bf16 Y, 4 elems/thread
__global__ __launch_bounds__(256) void li_scan_k(uint2* __restrict__ Y)
{
    const int n = blockIdx.x * 256 + threadIdx.x;
    float v[4] = {0.f, 0.f, 0.f, 0.f}, c[4] = {0.f, 0.f, 0.f, 0.f};
    #pragma unroll
    for (int t = 0; t < 16; ++t) {
        const size_t idx = (size_t)t * (SLICE / 4) + n;
        uint2 u = Y[idx];
        float x[4] = { bf2f((unsigned short)(u.x & 0xffff)), bf2f((unsigned short)(u.x >> 16)),
                       bf2f((unsigned short)(u.y & 0xffff)), bf2f((unsigned short)(u.y >> 16)) };
        #pragma unroll
        for (int e = 0; e < 4; ++e) {
            v[e] = v[e] + 0.1f * ((0.0f - v[e]) + c[e]);
            c[e] = c[e] - 0.2f * c[e] + x[e];
        }
        u.x = (unsigned)f2bf(v[0]) | ((unsigned)f2bf(v[1]) << 16);
        u.y = (unsigned)f2bf(v[2]) | ((unsigned)f2bf(v[3]) << 16);
        Y[idx] = u;
    }
}

// ---- 1x1 heads, 2 pixels/thread
__global__ __launch_bounds__(256) void heads_k(
    const unsigned int* __restrict__ V,
    const float* __restrict__ bw, const float* __restrict__ bb,
    const float* __restrict__ cw, const float* __restrict__ cb,
    float* __restrict__ out)
{
    const int n = blockIdx.x * 256 + threadIdx.x;
    const int tb  = n / (HWD / 2);
    const int hw2 = n - tb * (HWD / 2);
    const unsigned int* vp = V + (size_t)tb * CIN * (HWD / 2) + hw2;

    float b0[12], b1[12], cl0[9], cl1[9];
    #pragma unroll
    for (int o = 0; o < 12; ++o) { b0[o] = bb[o]; b1[o] = bb[o]; }
    #pragma unroll
    for (int o = 0; o < 9;  ++o) { cl0[o] = cb[o]; cl1[o] = cb[o]; }

    for (int ci = 0; ci < CIN; ++ci) {
        const unsigned u = vp[(size_t)ci * (HWD / 2)];
        const float lo = bf2f((unsigned short)(u & 0xffff));
        const float hi = bf2f((unsigned short)(u >> 16));
        #pragma unroll
        for (int o = 0; o < 12; ++o) {
            const float w = bw[o * CIN + ci];
            b0[o] += lo * w; b1[o] += hi * w;
        }
        #pragma unroll
        for (int o = 0; o < 9; ++o) {
            const float w = cw[o * CIN + ci];
            cl0[o] += lo * w; cl1[o] += hi * w;
        }
    }

    const int hw = hw2 * 2;
    float* ob = out + (size_t)tb * 12 * HWD + hw;
    #pragma unroll
    for (int o = 0; o < 12; ++o) { ob[(size_t)o * HWD] = b0[o]; ob[(size_t)o * HWD + 1] = b1[o]; }
    float* oc = out + (size_t)12 * NTB * HWD + (size_t)tb * 9 * HWD + hw;
    #pragma unroll
    for (int o = 0; o < 9;  ++o) { oc[(size_t)o * HWD] = cl0[o]; oc[(size_t)o * HWD + 1] = cl1[o]; }
}

extern "C" void kernel_launch(void* const* d_in, const int* in_sizes, int n_in,
                              void* d_out, int out_size, void* d_ws, size_t ws_size,
                              hipStream_t stream)
{
    const float* X   = (const float*)d_in[0];  // (16,4,256,48,48)
    const float* cw3 = (const float*)d_in[1];  // (256,256,3,3)
    const float* cb3 = (const float*)d_in[2];  // (256,)
    const float* bw  = (const float*)d_in[3];
    const float* bb  = (const float*)d_in[4];
    const float* clw = (const float*)d_in[5];
    const float* clb = (const float*)d_in[6];
    float* out = (float*)d_out;

    unsigned short* Xtp = (unsigned short*)((char*)d_ws + WS_XT);
    unsigned short* At  = (unsigned short*)((char*)d_ws + WS_AT);
    unsigned short* Y   = (unsigned short*)((char*)d_ws + WS_Y);

    hipMemsetAsync(Xtp, 0, 40960000, stream);   // halo zeros (covers both halves)
    prep_w_k<<<288, 256, 0, stream>>>(cw3, At);

    for (int half = 0; half < 2; ++half) {
        const float* Xh = X + (size_t)half * 32 * CIN * HWD;
        prep_x_k<<<dim3(36, 4, 32), 256, 0, stream>>>(Xh, Xtp);
        conv11_k<<<768, 256, 0, stream>>>(Xtp, At, cb3, Y, half * 32);
    }

    li_scan_k<<<SLICE / 1024, 256, 0, stream>>>((uint2*)Y);
    heads_k  <<<NTB * HWD / 512, 256, 0, stream>>>((const unsigned int*)Y,
                                                   bw, bb, clw, clb, out);
}